// Round 1
// baseline (907.931 us; speedup 1.0000x reference)
//
#include <hip/hip_runtime.h>
#include <math.h>

#define NL     24
#define HIDDEN 512
#define H3     1536
#define NHEADS 16
#define HD     32
#define CAPCTX 2048
#define FFD    2048
#define NVOCAB 1025
#define GRID   256
#define NT     256
#define EPSLN  1e-5f
#define ISQ    0.17677669529663687f  /* 1/sqrt(32) */

// ---- agent-scope (device-coherent, LLC) load/store helpers -----------------
__device__ __forceinline__ float gld(const float* p){ return __hip_atomic_load(p, __ATOMIC_RELAXED, __HIP_MEMORY_SCOPE_AGENT); }
__device__ __forceinline__ void  gst(float* p, float v){ __hip_atomic_store(p, v, __ATOMIC_RELAXED, __HIP_MEMORY_SCOPE_AGENT); }
__device__ __forceinline__ int   ild(const int* p){ return __hip_atomic_load(p, __ATOMIC_RELAXED, __HIP_MEMORY_SCOPE_AGENT); }
__device__ __forceinline__ void  ist(int* p, int v){ __hip_atomic_store(p, v, __ATOMIC_RELAXED, __HIP_MEMORY_SCOPE_AGENT); }

struct LdsG { float xload[HIDDEN]; float xn[HIDDEN]; float red[16*17]; float r8[8]; };
struct LdsA { float q[HD]; float sc[128]; float e[128]; float v[128*33]; float red[NT]; };
union  Lds  { LdsG g; LdsA a; };

// ---- grid barrier: arrive-slot + master(block0)-poll release ---------------
__device__ __forceinline__ void gridbar(int* arrive, int* release, int b, int tid, int tgt, int* sflag){
  __syncthreads();                       // drains this block's stores (vmcnt 0) -> data at LLC
  if (b == 0){
    int guard = 0;
    for(;;){
      if (tid == 0) *sflag = 1;
      __syncthreads();
      int ok = 1;
      if (tid > 0 && tid < GRID) ok = (ild(&arrive[tid]) >= tgt) ? 1 : 0;
      if (!ok) *sflag = 0;
      __syncthreads();
      int done = *sflag;
      __syncthreads();
      if (done) break;
      if (++guard > (1<<20)) break;      // safety: never hang the harness
    }
    if (tid == 0) ist(release, tgt);
  } else {
    if (tid == 0){
      ist(&arrive[b], tgt);
      int guard = 0;
      while (ild(release) < tgt){
        __builtin_amdgcn_s_sleep(1);
        if (++guard > (1<<20)) break;    // safety
      }
    }
    __syncthreads();
  }
  asm volatile("" ::: "memory");
}

// ---- block reduction of two sums over 256 threads --------------------------
__device__ __forceinline__ void bsum2(float &a, float &bb, float* lds8, int tid){
  #pragma unroll
  for (int o=32;o;o>>=1){ a += __shfl_down(a,o); bb += __shfl_down(bb,o); }
  __syncthreads();
  if ((tid&63)==0){ int w=tid>>6; lds8[w]=a; lds8[4+w]=bb; }
  __syncthreads();
  a  = lds8[0]+lds8[1]+lds8[2]+lds8[3];
  bb = lds8[4]+lds8[5]+lds8[6]+lds8[7];
  __syncthreads();
}

// ---- reconstruct t = x1 + b2 + sum(ff2 partials); xn = LN2(t) --------------
__device__ __forceinline__ void build_xn_from_t(const float* wx1, const float* wf2,
    const float* B2l, const float* NW2l, const float* NB2l,
    float* wx_out, LdsG* g, int tid)
{
  float s1=0.f, s2=0.f;
  for (int i=tid;i<HIDDEN;i+=NT){
    float t = gld(&wx1[i]) + B2l[i];
    #pragma unroll
    for (int rg=0; rg<8; rg++) t += gld(&wf2[rg*HIDDEN + i]);
    g->xload[i] = t; s1 += t; s2 += t*t;
  }
  bsum2(s1, s2, g->r8, tid);
  float mu   = s1*(1.f/HIDDEN);
  float rstd = rsqrtf(s2*(1.f/HIDDEN) - mu*mu + EPSLN);
  for (int i=tid;i<HIDDEN;i+=NT){
    float v = (g->xload[i]-mu)*rstd*NW2l[i] + NB2l[i];
    g->xn[i] = v;
    if (wx_out) gst(&wx_out[i], v);
  }
  __syncthreads();
}

// ---- 16-column GEMV slab: thread (c=tid&15, s=tid>>4); W pre-offset by j0 --
// returns the column sum (valid on threads tid<16, col = tid)
__device__ __forceinline__ float gemv16(const float* __restrict__ W, int stride, int depth,
                                        const float* xn, float* red, int tid){
  const int c = tid & 15, srow = tid >> 4;
  float acc = 0.f;
  #pragma unroll 8
  for (int i = srow; i < depth; i += 16) acc += xn[i] * W[(size_t)i*stride + c];
  red[srow*17 + c] = acc;
  __syncthreads();
  float dsum = 0.f;
  if (srow == 0){
    #pragma unroll
    for (int k=0;k<16;k++) dsum += red[k*17 + c];
  }
  __syncthreads();
  return dsum;
}

__global__ __launch_bounds__(NT, 2)
void t2s_decode(const int* __restrict__ LT, const int* __restrict__ PI, const int* __restrict__ CL,
                const float* __restrict__ KC, const float* __restrict__ VC,
                const float* __restrict__ EMB, const float* __restrict__ PE,
                const float* __restrict__ XSc, const float* __restrict__ ALp,
                const float* __restrict__ QKVW, const float* __restrict__ QKVB,
                const float* __restrict__ OUTW, const float* __restrict__ OUTB,
                const float* __restrict__ NW1, const float* __restrict__ NB1,
                const float* __restrict__ NW2, const float* __restrict__ NB2,
                const float* __restrict__ W1, const float* __restrict__ B1,
                const float* __restrict__ W2, const float* __restrict__ B2,
                const float* __restrict__ PW, const float* __restrict__ PB,
                float* __restrict__ OUT, float* __restrict__ WS)
{
  __shared__ Lds L;
  __shared__ int sflag;
  const int b = blockIdx.x, tid = threadIdx.x;

  int* arrive  = (int*)WS;          // [256]
  int* release = arrive + GRID;     // [1]
  float* F    = WS + 512;           // float area (byte 2048+)
  float* wx   = F;                  // [512]  layer input x (post-LN2 / xy)
  float* wx1  = F + 512;            // [512]  LN1 output
  float* wqkv = F + 1024;           // [1536] q(pre-scaled)|k|v
  float* wsv  = F + 2560;           // [512]  s = x + attn_out_proj
  float* wh   = F + 3072;           // [2048] ff1 output
  float* wpart= F + 5120;           // [16*16*34] attn partials (m,S,o[32])
  float* wf2  = F + 13824;          // [8*512] ff2 partials

  float* KO = OUT + 1029;
  float* VO = KO + (size_t)NL*CAPCTX*HIDDEN;

  const int token = LT[0], posi = PI[0], clen = CL[0], nlen = clen + 1;
  int stage = 0;

  // ---- INIT: xy = emb[token]*x_scale + alpha*pe[pos] -----------------------
  if (b == 0){
    float xs = XSc[0], al = ALp[0];
    for (int i=tid;i<HIDDEN;i+=NT)
      gst(&wx[i], EMB[(size_t)token*HIDDEN+i]*xs + al*PE[(size_t)posi*HIDDEN+i]);
  }
  gridbar(arrive, release, b, tid, ++stage, &sflag);

  for (int l=0; l<NL; l++){
    // ---- S1: qkv GEMV (blocks 0..95, 16 cols each) + tail-zero (96..255) ---
    if (b < 96){
      if (l == 0){
        for (int i=tid;i<HIDDEN;i+=NT) L.g.xn[i] = gld(&wx[i]);
        __syncthreads();
      } else {
        build_xn_from_t(wx1, wf2, B2+(size_t)(l-1)*HIDDEN,
                        NW2+(size_t)(l-1)*HIDDEN, NB2+(size_t)(l-1)*HIDDEN,
                        (b==0)? wx : nullptr, &L.g, tid);
      }
      const int j0 = b << 4;
      float dsum = gemv16(QKVW + (size_t)l*HIDDEN*H3 + j0, H3, HIDDEN, L.g.xn, L.g.red, tid);
      if (tid < 16){
        int j = j0 + tid;
        float val = dsum + QKVB[(size_t)l*H3 + j];
        if (j < HIDDEN) val *= ISQ;                 // pre-scale q by 1/sqrt(d)
        gst(&wqkv[j], val);
        // write new k/v cache slot row
        if (j >= HIDDEN && j < 2*HIDDEN)  KO[((size_t)l*CAPCTX + clen)*HIDDEN + (j-HIDDEN)]   = val;
        else if (j >= 2*HIDDEN)           VO[((size_t)l*CAPCTX + clen)*HIDDEN + (j-2*HIDDEN)] = val;
      }
    } else {
      // zero tail rows [nlen, CAP) of k_out and v_out for this layer
      const int nz = CAPCTX - nlen;
      const int total = 2*nz;
      const float4 z4 = make_float4(0.f,0.f,0.f,0.f);
      for (int r = b - 96; r < total; r += 160){
        const int isv = (r >= nz);
        const int p = nlen + (isv ? r - nz : r);
        float4* dst = (float4*)((isv ? VO : KO) + ((size_t)l*CAPCTX + p)*HIDDEN);
        for (int i=tid; i<HIDDEN/4; i+=NT) dst[i] = z4;
      }
    }
    gridbar(arrive, release, b, tid, ++stage, &sflag);

    // ---- S2: attention partials, block=(head, pos-chunk of 128); fused copy -
    {
      const int h = b >> 4, cch = b & 15;
      const int p0 = cch << 7;
      if (tid < HD) L.a.q[tid] = gld(&wqkv[h*HD + tid]);
      __syncthreads();
      const int p = p0 + (tid >> 1);
      const int half = tid & 1, dbase = half*16;
      const bool valid = (p < nlen);
      const size_t rowoff = ((size_t)l*CAPCTX + p)*HIDDEN + h*HD + dbase;
      float dotp = 0.f;
      float vbuf[16];
      if (valid){
        if (p == clen){
          #pragma unroll
          for (int k=0;k<16;k++){ float kv = gld(&wqkv[HIDDEN + h*HD + dbase + k]); dotp += kv * L.a.q[dbase+k]; }
        } else {
          const float4* src = (const float4*)(KC + rowoff);
          float4* dst = (float4*)(KO + rowoff);
          #pragma unroll
          for (int k4=0;k4<4;k4++){
            float4 v4 = src[k4]; dst[k4] = v4;   // fused k-cache copy
            dotp += v4.x*L.a.q[dbase+4*k4] + v4.y*L.a.q[dbase+4*k4+1]
                  + v4.z*L.a.q[dbase+4*k4+2] + v4.w*L.a.q[dbase+4*k4+3];
          }
        }
      }
      dotp += __shfl_xor(dotp, 1);
      if (half == 0) L.a.sc[tid>>1] = valid ? dotp : -1e30f;
      if (valid){
        if (p == clen){
          #pragma unroll
          for (int k=0;k<16;k++) vbuf[k] = gld(&wqkv[2*HIDDEN + h*HD + dbase + k]);
        } else {
          const float4* srcv = (const float4*)(VC + rowoff);
          float4* dstv = (float4*)(VO + rowoff);
          #pragma unroll
          for (int k4=0;k4<4;k4++){
            float4 v4 = srcv[k4]; dstv[k4] = v4; // fused v-cache copy
            vbuf[4*k4]=v4.x; vbuf[4*k4+1]=v4.y; vbuf[4*k4+2]=v4.z; vbuf[4*k4+3]=v4.w;
          }
        }
      } else {
        #pragma unroll
        for (int k=0;k<16;k++) vbuf[k]=0.f;
      }
      #pragma unroll
      for (int k=0;k<16;k++) L.a.v[(p-p0)*33 + dbase + k] = vbuf[k];
      __syncthreads();
      // chunk max
      float m = (tid < 128) ? L.a.sc[tid] : -1e30f;
      #pragma unroll
      for (int o=32;o;o>>=1) m = fmaxf(m, __shfl_xor(m, o));
      if ((tid&63)==0) L.a.red[tid>>6] = m;
      __syncthreads();
      m = fmaxf(fmaxf(L.a.red[0],L.a.red[1]), fmaxf(L.a.red[2],L.a.red[3]));
      __syncthreads();
      // exp + sum
      float e = 0.f;
      if (tid < 128){
        int pp = p0 + tid;
        e = (pp < nlen) ? expf(L.a.sc[tid] - m) : 0.f;
        L.a.e[tid] = e;
      }
      float ssum = e;
      #pragma unroll
      for (int o=32;o;o>>=1) ssum += __shfl_xor(ssum, o);
      if ((tid&63)==0) L.a.red[tid>>6] = ssum;
      __syncthreads();
      ssum = L.a.red[0]+L.a.red[1]+L.a.red[2]+L.a.red[3];
      __syncthreads();
      // o partial: thread (d, grp) sums 16 positions
      const int d = tid & 31, grp = tid >> 5;
      float oacc = 0.f;
      #pragma unroll
      for (int q2=0;q2<16;q2++){ int pp = (grp<<4) + q2; oacc += L.a.e[pp] * L.a.v[pp*33 + d]; }
      L.a.red[tid] = oacc;
      __syncthreads();
      float* rec = &wpart[(size_t)(h*16 + cch)*34];
      if (tid < 32){
        float o8 = 0.f;
        #pragma unroll
        for (int g=0; g<8; g++) o8 += L.a.red[tid + (g<<5)];
        gst(&rec[2+tid], o8);
      }
      if (tid == 0){ gst(&rec[0], m); gst(&rec[1], ssum); }
    }
    gridbar(arrive, release, b, tid, ++stage, &sflag);

    // ---- S4: softmax combine (redundant) + out-proj + residual (blocks 0..31)
    if (b < 32){
      const int hh = tid >> 4, cc = tid & 15;
      const float* rec = &wpart[(size_t)(hh*16 + cc)*34];
      float m = gld(&rec[0]);
      float s = gld(&rec[1]);
      float M = m;
      #pragma unroll
      for (int o=1;o<16;o<<=1) M = fmaxf(M, __shfl_xor(M, o));
      float wc = expf(m - M);
      float Ssum = wc * s;
      #pragma unroll
      for (int o=1;o<16;o<<=1) Ssum += __shfl_xor(Ssum, o);
      float inv = 1.f / Ssum;
      float ov[HD];
      #pragma unroll
      for (int dd=0; dd<HD; dd++) ov[dd] = gld(&rec[2+dd]);
      #pragma unroll
      for (int dd=0; dd<HD; dd++){
        float t = ov[dd] * wc;
        #pragma unroll
        for (int o=1;o<16;o<<=1) t += __shfl_xor(t, o);
        if (cc == 0) L.g.xn[hh*HD + dd] = t * inv;
      }
      __syncthreads();
      const int j0 = b << 4;
      float dsum = gemv16(OUTW + (size_t)l*HIDDEN*HIDDEN + j0, HIDDEN, HIDDEN, L.g.xn, L.g.red, tid);
      if (tid < 16){
        int j = j0 + tid;
        float o2 = dsum + OUTB[(size_t)l*HIDDEN + j];
        gst(&wsv[j], gld(&wx[j]) + o2);
      }
    }
    gridbar(arrive, release, b, tid, ++stage, &sflag);

    // ---- S5: LN1 (redundant stats) + FF1 relu (blocks 0..127) --------------
    if (b < 128){
      float s1=0.f, s2=0.f;
      for (int i=tid;i<HIDDEN;i+=NT){ float v = gld(&wsv[i]); L.g.xload[i]=v; s1+=v; s2+=v*v; }
      bsum2(s1, s2, L.g.r8, tid);
      float mu = s1*(1.f/HIDDEN), rstd = rsqrtf(s2*(1.f/HIDDEN)-mu*mu+EPSLN);
      for (int i=tid;i<HIDDEN;i+=NT){
        float xx = (L.g.xload[i]-mu)*rstd*NW1[(size_t)l*HIDDEN+i] + NB1[(size_t)l*HIDDEN+i];
        L.g.xn[i]=xx;
        if (b==0) gst(&wx1[i], xx);
      }
      __syncthreads();
      const int j0 = b << 4;
      float dsum = gemv16(W1 + (size_t)l*HIDDEN*FFD + j0, FFD, HIDDEN, L.g.xn, L.g.red, tid);
      if (tid < 16){
        int j = j0 + tid;
        gst(&wh[j], fmaxf(dsum + B1[(size_t)l*FFD + j], 0.f));
      }
    }
    gridbar(arrive, release, b, tid, ++stage, &sflag);

    // ---- S6: FF2 partials (all 256: cg 0..31 x rg 0..7) --------------------
    {
      const int cg = b >> 3, rg = b & 7;
      L.g.xload[tid] = gld(&wh[rg*256 + tid]);
      __syncthreads();
      const int j0 = cg << 4;
      float dsum = gemv16(W2 + (size_t)l*FFD*HIDDEN + (size_t)rg*256*HIDDEN + j0,
                          HIDDEN, 256, L.g.xload, L.g.red, tid);
      if (tid < 16) gst(&wf2[rg*HIDDEN + j0 + tid], dsum);
    }
    gridbar(arrive, release, b, tid, ++stage, &sflag);
  }

  // ---- pred logits (blocks 0..64, 16 rows each; pred_w rows are contiguous)
  if (b < 65){
    build_xn_from_t(wx1, wf2, B2+(size_t)23*HIDDEN, NW2+(size_t)23*HIDDEN, NB2+(size_t)23*HIDDEN,
                    nullptr, &L.g, tid);
    const int v0 = b << 4;
    const int nrows = (b == 64) ? 1 : 16;
    const int rr = tid >> 4, s2l = tid & 15;
    if (rr < nrows){
      const float* row = PW + (size_t)(v0+rr)*HIDDEN;
      float acc = 0.f;
      #pragma unroll 8
      for (int mm=0; mm<32; mm++){ int i = s2l + (mm<<4); acc += L.g.xn[i] * row[i]; }
      #pragma unroll
      for (int o=1;o<16;o<<=1) acc += __shfl_xor(acc, o);
      if (s2l == 0) gst(&OUT[v0+rr], acc + PB[v0+rr]);
    }
  }
  gridbar(arrive, release, b, tid, ++stage, &sflag);

  // ---- final: first-max argmax + scalar outputs (block 0) ------------------
  if (b == 0){
    float bv = -3.0e38f; int bi = 0;
    for (int v=tid; v<NVOCAB; v+=NT){
      float x = gld(&OUT[v]);
      if (x > bv){ bv = x; bi = v; }
    }
    L.g.xload[tid] = bv;
    ((int*)L.g.xn)[tid] = bi;
    __syncthreads();
    for (int step=128; step; step>>=1){
      if (tid < step){
        float ov2 = L.g.xload[tid+step]; int oi = ((int*)L.g.xn)[tid+step];
        float mv  = L.g.xload[tid];      int mi = ((int*)L.g.xn)[tid];
        if (ov2 > mv || (ov2 == mv && oi < mi)){ L.g.xload[tid]=ov2; ((int*)L.g.xn)[tid]=oi; }
      }
      __syncthreads();
    }
    if (tid == 0){
      int bi0 = ((int*)L.g.xn)[0];
      OUT[NVOCAB]   = (float)bi0;                  // sampled
      OUT[NVOCAB+1] = (bi0 == 1024) ? 1.f : 0.f;   // eos
      OUT[NVOCAB+2] = (float)nlen;                 // next_len
      OUT[NVOCAB+3] = (float)(posi + 1);           // next_pos
    }
  }
}

extern "C" void kernel_launch(void* const* d_in, const int* in_sizes, int n_in,
                              void* d_out, int out_size, void* d_ws, size_t ws_size,
                              hipStream_t stream) {
  (void)in_sizes; (void)n_in; (void)out_size; (void)ws_size;
  // zero the barrier area (arrive[256] + release) every call (replay-safe)
  hipMemsetAsync(d_ws, 0, 2048, stream);
  t2s_decode<<<GRID, NT, 0, stream>>>(
    (const int*)d_in[0], (const int*)d_in[1], (const int*)d_in[2],
    (const float*)d_in[3], (const float*)d_in[4],
    (const float*)d_in[5], (const float*)d_in[6],
    (const float*)d_in[7], (const float*)d_in[8],
    (const float*)d_in[9], (const float*)d_in[10],
    (const float*)d_in[11], (const float*)d_in[12],
    (const float*)d_in[13], (const float*)d_in[14],
    (const float*)d_in[15], (const float*)d_in[16],
    (const float*)d_in[17], (const float*)d_in[18],
    (const float*)d_in[19], (const float*)d_in[20],
    (const float*)d_in[21], (const float*)d_in[22],
    (float*)d_out, (float*)d_ws);
}